// Round 1
// baseline (1846.461 us; speedup 1.0000x reference)
//
#include <hip/hip_runtime.h>
#include <math.h>

// SimpleGCN diffusion on MI355X.
// Pipeline per call (all on `stream`, graph-capture safe):
//   1) degree histograms (row counts for CSR, col counts for gcn_norm)
//   2) dinv_ns / dinv_sl  (D^-1/2, without / with self loops; degree over COL per reference)
//   3) exclusive scan of row counts -> row_ptr; atomic-cursor fill -> csr_col
//   4) h = relu(x@W1)@W2   (wave-per-row, weights in LDS)
//   5) K=4 diffusion steps: k_grad (Perona-Malik gradient) + k_update (Ax,Gx SpMM + blend)
//   6) logits = relu(xk)@W3, log_softmax -> d_out

#define WAVE 64

__global__ void k_count(const int* __restrict__ row, const int* __restrict__ col,
                        int* __restrict__ cnt, int* __restrict__ deg, int E) {
    int e = blockIdx.x * blockDim.x + threadIdx.x;
    if (e < E) {
        atomicAdd(&cnt[row[e]], 1);   // CSR row sizes
        atomicAdd(&deg[col[e]], 1);   // gcn_norm degree (reference segments over col)
    }
}

__global__ void k_dinv(const int* __restrict__ deg, float* __restrict__ dinv_ns,
                       float* __restrict__ dinv_sl, int N) {
    int i = blockIdx.x * blockDim.x + threadIdx.x;
    if (i < N) {
        int d = deg[i];
        dinv_ns[i] = d > 0 ? rsqrtf((float)d) : 0.0f;
        dinv_sl[i] = rsqrtf((float)(d + 1));
    }
}

// ---- 2-level exclusive scan over N row counts (N <= 131072: block sums fit one block) ----
__global__ void k_scan1(const int* __restrict__ cnt, int* __restrict__ excl,
                        int* __restrict__ bsums, int N) {
    __shared__ int s[256];
    int i = blockIdx.x * 256 + threadIdx.x;
    int v = (i < N) ? cnt[i] : 0;
    s[threadIdx.x] = v;
    __syncthreads();
    for (int off = 1; off < 256; off <<= 1) {
        int t = (threadIdx.x >= off) ? s[threadIdx.x - off] : 0;
        __syncthreads();
        s[threadIdx.x] += t;
        __syncthreads();
    }
    if (i < N) excl[i] = s[threadIdx.x] - v;           // exclusive within block
    if (threadIdx.x == 255) bsums[blockIdx.x] = s[255];
}

__global__ void k_scan2(int* __restrict__ bsums, int nb) {
    __shared__ int s[512];
    int t = threadIdx.x;
    int v = (t < nb) ? bsums[t] : 0;
    s[t] = v;
    __syncthreads();
    for (int off = 1; off < 512; off <<= 1) {
        int u = (t >= off) ? s[t - off] : 0;
        __syncthreads();
        s[t] += u;
        __syncthreads();
    }
    if (t < nb) bsums[t] = s[t] - v;                   // exclusive block offsets
}

__global__ void k_scan3(int* __restrict__ rp, int* __restrict__ cursor,
                        const int* __restrict__ bsums, int N, int E) {
    int i = blockIdx.x * 256 + threadIdx.x;
    if (i < N) {
        int v = rp[i] + bsums[blockIdx.x];
        rp[i] = v;
        cursor[i] = v;
    }
    if (i == 0) rp[N] = E;
}

__global__ void k_fill(const int* __restrict__ row, const int* __restrict__ col,
                       int* __restrict__ cursor, int* __restrict__ ccol, int E) {
    int e = blockIdx.x * blockDim.x + threadIdx.x;
    if (e < E) {
        int p = atomicAdd(&cursor[row[e]], 1);
        ccol[p] = col[e];
    }
}

// ---- h = relu(x @ W1) @ W2 ; wave-per-row, 64x64 weights in LDS ----
__global__ __launch_bounds__(256) void k_mlp(const float* __restrict__ x,
                                             const float* __restrict__ W1,
                                             const float* __restrict__ W2,
                                             float* __restrict__ h, int N) {
    __shared__ float sW1[64 * 64];
    __shared__ float sW2[64 * 64];
    __shared__ float sbuf[4][64];
    for (int t = threadIdx.x; t < 4096; t += 256) { sW1[t] = W1[t]; sW2[t] = W2[t]; }
    __syncthreads();
    int wid = threadIdx.x >> 6, f = threadIdx.x & 63;
    int i = blockIdx.x * 4 + wid;
    bool ok = i < N;
    int ii = ok ? i : 0;
    float xr = x[(size_t)ii * 64 + f];
    sbuf[wid][f] = xr;
    __syncthreads();
    float t0 = 0.f;
#pragma unroll
    for (int k = 0; k < 64; ++k) t0 = fmaf(sbuf[wid][k], sW1[k * 64 + f], t0);
    t0 = fmaxf(t0, 0.f);
    __syncthreads();
    sbuf[wid][f] = t0;
    __syncthreads();
    float hv = 0.f;
#pragma unroll
    for (int k = 0; k < 64; ++k) hv = fmaf(sbuf[wid][k], sW2[k * 64 + f], hv);
    if (ok) h[(size_t)i * 64 + f] = hv;
}

// ---- g[i] = sum_{e:row==i} w_ns * (0.5*exp(-|d|^2/2)) * d,  d = xk[col]-xk[i] ----
__global__ __launch_bounds__(256) void k_grad(const float* __restrict__ xk,
                                              const int* __restrict__ rp,
                                              const int* __restrict__ ccol,
                                              const float* __restrict__ dinv,
                                              float* __restrict__ g, int N) {
    int i = (blockIdx.x * blockDim.x + threadIdx.x) >> 6;
    int f = threadIdx.x & 63;
    if (i >= N) return;
    float xi = xk[(size_t)i * 64 + f];
    float di = dinv[i];
    float acc = 0.f;
    int e0 = rp[i], e1 = rp[i + 1];
    for (int e = e0; e < e1; ++e) {
        int c = ccol[e];
        float d = xk[(size_t)c * 64 + f] - xi;
        float n2 = d * d;
#pragma unroll
        for (int off = 32; off; off >>= 1) n2 += __shfl_xor(n2, off);
        float w = di * dinv[c];
        float coef = w * 0.5f * __expf(-0.5f * n2);
        acc = fmaf(coef, d, acc);
    }
    g[(size_t)i * 64 + f] = acc;
}

// ---- xk_new = 0.1*h + 0.2*xk + 0.7*Ax + 0.14*Gx  (Ax,Gx incl. analytic self-loop) ----
__global__ __launch_bounds__(256) void k_update(const float* __restrict__ xk,
                                                const float* __restrict__ g,
                                                const float* __restrict__ h,
                                                const int* __restrict__ rp,
                                                const int* __restrict__ ccol,
                                                const float* __restrict__ dinv_sl,
                                                float* __restrict__ xo, int N) {
    int i = (blockIdx.x * blockDim.x + threadIdx.x) >> 6;
    int f = threadIdx.x & 63;
    if (i >= N) return;
    float xi = xk[(size_t)i * 64 + f];
    float gi = g[(size_t)i * 64 + f];
    float dsl = dinv_sl[i];
    float ws = dsl * dsl;                 // self-loop weight
    float aa = ws * xi;
    float ag = ws * gi;
    int e0 = rp[i], e1 = rp[i + 1];
    for (int e = e0; e < e1; ++e) {
        int c = ccol[e];
        float w = dsl * dinv_sl[c];
        aa = fmaf(w, xk[(size_t)c * 64 + f], aa);
        ag = fmaf(w, g[(size_t)c * 64 + f], ag);
    }
    xo[(size_t)i * 64 + f] = 0.1f * h[(size_t)i * 64 + f] + 0.2f * xi + 0.7f * aa + 0.14f * ag;
}

// ---- out = log_softmax(relu(xk) @ W3) ; wave-per-row; C=40 lanes active for output ----
__global__ __launch_bounds__(256) void k_out(const float* __restrict__ xk,
                                             const float* __restrict__ W3,
                                             float* __restrict__ out, int N, int C) {
    __shared__ float sW3[64 * 40];
    __shared__ float sbuf[4][64];
    for (int t = threadIdx.x; t < 64 * 40; t += 256) sW3[t] = W3[t];
    __syncthreads();
    int wid = threadIdx.x >> 6, f = threadIdx.x & 63;
    int i = blockIdx.x * 4 + wid;
    bool ok = i < N;
    int ii = ok ? i : 0;
    float xv = fmaxf(xk[(size_t)ii * 64 + f], 0.f);
    sbuf[wid][f] = xv;
    __syncthreads();
    float acc = 0.f;
    if (f < C) {
#pragma unroll
        for (int k = 0; k < 64; ++k) acc = fmaf(sbuf[wid][k], sW3[k * 40 + f], acc);
    }
    float m = (f < C) ? acc : -INFINITY;
#pragma unroll
    for (int off = 32; off; off >>= 1) m = fmaxf(m, __shfl_xor(m, off));
    float ex = (f < C) ? __expf(acc - m) : 0.f;
    float s = ex;
#pragma unroll
    for (int off = 32; off; off >>= 1) s += __shfl_xor(s, off);
    if (ok && f < C) out[(size_t)i * C + f] = acc - m - logf(s);
}

extern "C" void kernel_launch(void* const* d_in, const int* in_sizes, int n_in,
                              void* d_out, int out_size, void* d_ws, size_t ws_size,
                              hipStream_t stream) {
    const float* x  = (const float*)d_in[0];
    const int*   ei = (const int*)d_in[1];
    const float* W1 = (const float*)d_in[2];
    const float* W2 = (const float*)d_in[3];
    const float* W3 = (const float*)d_in[4];
    float* out = (float*)d_out;

    const int N = in_sizes[0] / 64;        // F = 64
    const int E = in_sizes[1] / 2;
    const int C = in_sizes[4] / 64;        // 40
    const int* row = ei;
    const int* col = ei + E;

    // workspace carve-out (256B aligned)
    char* w = (char*)d_ws;
    auto alloc = [&](size_t bytes) -> char* {
        char* p = w;
        w += (bytes + 255) & ~(size_t)255;
        return p;
    };
    int*   cnt     = (int*)alloc((size_t)N * 4);
    int*   deg     = (int*)alloc((size_t)N * 4);
    int*   rp      = (int*)alloc((size_t)(N + 1) * 4);
    int*   cursor  = (int*)alloc((size_t)N * 4);
    int*   bsums   = (int*)alloc(4096);
    float* dinv_ns = (float*)alloc((size_t)N * 4);
    float* dinv_sl = (float*)alloc((size_t)N * 4);
    int*   ccol    = (int*)alloc((size_t)E * 4);
    float* h       = (float*)alloc((size_t)N * 64 * 4);
    float* xa      = (float*)alloc((size_t)N * 64 * 4);
    float* xb      = (float*)alloc((size_t)N * 64 * 4);
    float* g       = (float*)alloc((size_t)N * 64 * 4);
    (void)ws_size; (void)n_in; (void)out_size;

    hipMemsetAsync(cnt, 0, (size_t)N * 4, stream);
    hipMemsetAsync(deg, 0, (size_t)N * 4, stream);

    const int eb    = (E + 255) / 256;
    const int nb256 = (N + 255) / 256;
    const int nb4   = (N + 3) / 4;

    k_count<<<eb, 256, 0, stream>>>(row, col, cnt, deg, E);
    k_dinv<<<nb256, 256, 0, stream>>>(deg, dinv_ns, dinv_sl, N);
    k_scan1<<<nb256, 256, 0, stream>>>(cnt, rp, bsums, N);
    k_scan2<<<1, 512, 0, stream>>>(bsums, nb256);
    k_scan3<<<nb256, 256, 0, stream>>>(rp, cursor, bsums, N, E);
    k_fill<<<eb, 256, 0, stream>>>(row, col, cursor, ccol, E);

    k_mlp<<<nb4, 256, 0, stream>>>(x, W1, W2, h, N);

    const float* cur = h;
    float* nxt = xa;
    for (int k = 0; k < 4; ++k) {
        k_grad<<<nb4, 256, 0, stream>>>(cur, rp, ccol, dinv_ns, g, N);
        k_update<<<nb4, 256, 0, stream>>>(cur, g, h, rp, ccol, dinv_sl, nxt, N);
        cur = nxt;
        nxt = (nxt == xa) ? xb : xa;
    }

    k_out<<<nb4, 256, 0, stream>>>(cur, W3, out, N, C);
}

// Round 2
// 1020.348 us; speedup vs baseline: 1.8096x; 1.8096x over previous
//
#include <hip/hip_runtime.h>
#include <math.h>

// SimpleGCN diffusion on MI355X — round 2.
// Per diffusion step, two kernels:
//   K1 (k_step1): one xk[col] gather per edge -> BOTH Perona-Malik gradient g
//                 AND Ax accumulation; writes g and part = 0.1h + 0.2xk + 0.7*Ax_sl.
//   K2 (k_step2): one g[col] gather per edge -> Gx; writes xo = part + 0.14*Gx (in place).
// Edge loop uses float4 lanes (16 lanes per 64-f vector) so each wave keeps
// 4 edges in flight (4 independent gather->reduce->fma chains).

__global__ void k_count(const int* __restrict__ row, const int* __restrict__ col,
                        int* __restrict__ cnt, int* __restrict__ deg, int E) {
    int e = blockIdx.x * blockDim.x + threadIdx.x;
    if (e < E) {
        atomicAdd(&cnt[row[e]], 1);   // CSR row sizes
        atomicAdd(&deg[col[e]], 1);   // gcn_norm degree (reference segments over col)
    }
}

__global__ void k_dinv(const int* __restrict__ deg, float2* __restrict__ dinv2, int N) {
    int i = blockIdx.x * blockDim.x + threadIdx.x;
    if (i < N) {
        int d = deg[i];
        float2 v;
        v.x = d > 0 ? rsqrtf((float)d) : 0.0f;     // no-self-loop norm
        v.y = rsqrtf((float)(d + 1));              // self-loop norm
        dinv2[i] = v;
    }
}

// ---- 2-level exclusive scan over N row counts ----
__global__ void k_scan1(const int* __restrict__ cnt, int* __restrict__ excl,
                        int* __restrict__ bsums, int N) {
    __shared__ int s[256];
    int i = blockIdx.x * 256 + threadIdx.x;
    int v = (i < N) ? cnt[i] : 0;
    s[threadIdx.x] = v;
    __syncthreads();
    for (int off = 1; off < 256; off <<= 1) {
        int t = (threadIdx.x >= off) ? s[threadIdx.x - off] : 0;
        __syncthreads();
        s[threadIdx.x] += t;
        __syncthreads();
    }
    if (i < N) excl[i] = s[threadIdx.x] - v;
    if (threadIdx.x == 255) bsums[blockIdx.x] = s[255];
}

__global__ void k_scan2(int* __restrict__ bsums, int nb) {
    __shared__ int s[512];
    int t = threadIdx.x;
    int v = (t < nb) ? bsums[t] : 0;
    s[t] = v;
    __syncthreads();
    for (int off = 1; off < 512; off <<= 1) {
        int u = (t >= off) ? s[t - off] : 0;
        __syncthreads();
        s[t] += u;
        __syncthreads();
    }
    if (t < nb) bsums[t] = s[t] - v;
}

__global__ void k_scan3(int* __restrict__ rp, int* __restrict__ cursor,
                        const int* __restrict__ bsums, int N, int E) {
    int i = blockIdx.x * 256 + threadIdx.x;
    if (i < N) {
        int v = rp[i] + bsums[blockIdx.x];
        rp[i] = v;
        cursor[i] = v;
    }
    if (i == 0) rp[N] = E;
}

__global__ void k_fill(const int* __restrict__ row, const int* __restrict__ col,
                       int* __restrict__ cursor, int* __restrict__ ccol, int E) {
    int e = blockIdx.x * blockDim.x + threadIdx.x;
    if (e < E) {
        int p = atomicAdd(&cursor[row[e]], 1);
        ccol[p] = col[e];
    }
}

// ---- h = relu(x @ W1) @ W2 ; wave-per-row, 64x64 weights in LDS ----
__global__ __launch_bounds__(256) void k_mlp(const float* __restrict__ x,
                                             const float* __restrict__ W1,
                                             const float* __restrict__ W2,
                                             float* __restrict__ h, int N) {
    __shared__ float sW1[64 * 64];
    __shared__ float sW2[64 * 64];
    __shared__ float sbuf[4][64];
    for (int t = threadIdx.x; t < 4096; t += 256) { sW1[t] = W1[t]; sW2[t] = W2[t]; }
    __syncthreads();
    int wid = threadIdx.x >> 6, f = threadIdx.x & 63;
    int i = blockIdx.x * 4 + wid;
    bool ok = i < N;
    int ii = ok ? i : 0;
    float xr = x[(size_t)ii * 64 + f];
    sbuf[wid][f] = xr;
    __syncthreads();
    float t0 = 0.f;
#pragma unroll
    for (int k = 0; k < 64; ++k) t0 = fmaf(sbuf[wid][k], sW1[k * 64 + f], t0);
    t0 = fmaxf(t0, 0.f);
    __syncthreads();
    sbuf[wid][f] = t0;
    __syncthreads();
    float hv = 0.f;
#pragma unroll
    for (int k = 0; k < 64; ++k) hv = fmaf(sbuf[wid][k], sW2[k * 64 + f], hv);
    if (ok) h[(size_t)i * 64 + f] = hv;
}

// ---- K1: gather xk[col] once; accumulate gradient g AND Ax; write g, part ----
// g[i]    = sum_e w_ns * 0.5*exp(-|d|^2/2) * d            (d = xk[c]-xk[i])
// part[i] = 0.1*h[i] + 0.2*xk[i] + 0.7*( ws*xk[i] + sum_e w_sl*xk[c] )
__global__ __launch_bounds__(256) void k_step1(const float* __restrict__ xk,
                                               const float* __restrict__ h,
                                               const int* __restrict__ rp,
                                               const int* __restrict__ ccol,
                                               const float2* __restrict__ dinv2,
                                               float* __restrict__ g,
                                               float* __restrict__ part, int N) {
    int i = (blockIdx.x * blockDim.x + threadIdx.x) >> 6;
    if (i >= N) return;
    int lane = threadIdx.x & 63;
    int grp = lane >> 4, sl = lane & 15;
    const float4* xk4 = (const float4*)xk;
    float4 xi = xk4[(size_t)i * 16 + sl];
    float2 dvi = dinv2[i];
    float4 ga = make_float4(0.f, 0.f, 0.f, 0.f);
    float4 aa = make_float4(0.f, 0.f, 0.f, 0.f);
    int e0 = rp[i], e1 = rp[i + 1];
    for (int e = e0 + grp; e < e1; e += 4) {
        int c = ccol[e];
        float4 xc = xk4[(size_t)c * 16 + sl];
        float dx = xc.x - xi.x, dy = xc.y - xi.y, dz = xc.z - xi.z, dw = xc.w - xi.w;
        float n2 = dx * dx + dy * dy + dz * dz + dw * dw;
        n2 += __shfl_xor(n2, 1);
        n2 += __shfl_xor(n2, 2);
        n2 += __shfl_xor(n2, 4);
        n2 += __shfl_xor(n2, 8);
        float2 dvc = dinv2[c];
        float coef = dvi.x * dvc.x * 0.5f * __expf(-0.5f * n2);
        float wsl = dvi.y * dvc.y;
        ga.x = fmaf(coef, dx, ga.x); ga.y = fmaf(coef, dy, ga.y);
        ga.z = fmaf(coef, dz, ga.z); ga.w = fmaf(coef, dw, ga.w);
        aa.x = fmaf(wsl, xc.x, aa.x); aa.y = fmaf(wsl, xc.y, aa.y);
        aa.z = fmaf(wsl, xc.z, aa.z); aa.w = fmaf(wsl, xc.w, aa.w);
    }
    // combine the 4 edge-groups (each already holds full feature coverage in 16 lanes)
#pragma unroll
    for (int off = 16; off <= 32; off <<= 1) {
        ga.x += __shfl_xor(ga.x, off); ga.y += __shfl_xor(ga.y, off);
        ga.z += __shfl_xor(ga.z, off); ga.w += __shfl_xor(ga.w, off);
        aa.x += __shfl_xor(aa.x, off); aa.y += __shfl_xor(aa.y, off);
        aa.z += __shfl_xor(aa.z, off); aa.w += __shfl_xor(aa.w, off);
    }
    if (lane < 16) {
        float ws = dvi.y * dvi.y;   // self-loop weight
        float4 hv = ((const float4*)h)[(size_t)i * 16 + sl];
        float4 o;
        o.x = 0.1f * hv.x + 0.2f * xi.x + 0.7f * fmaf(ws, xi.x, aa.x);
        o.y = 0.1f * hv.y + 0.2f * xi.y + 0.7f * fmaf(ws, xi.y, aa.y);
        o.z = 0.1f * hv.z + 0.2f * xi.z + 0.7f * fmaf(ws, xi.z, aa.z);
        o.w = 0.1f * hv.w + 0.2f * xi.w + 0.7f * fmaf(ws, xi.w, aa.w);
        ((float4*)g)[(size_t)i * 16 + sl] = ga;
        ((float4*)part)[(size_t)i * 16 + sl] = o;
    }
}

// ---- K2: gather g[col]; xo = part + 0.14*( ws*g[i] + sum_e w_sl*g[c] ) ----
__global__ __launch_bounds__(256) void k_step2(const float* __restrict__ g,
                                               const float* __restrict__ part,
                                               const int* __restrict__ rp,
                                               const int* __restrict__ ccol,
                                               const float2* __restrict__ dinv2,
                                               float* __restrict__ xo, int N) {
    int i = (blockIdx.x * blockDim.x + threadIdx.x) >> 6;
    if (i >= N) return;
    int lane = threadIdx.x & 63;
    int grp = lane >> 4, sl = lane & 15;
    const float4* g4 = (const float4*)g;
    float2 dvi = dinv2[i];
    float4 ga = make_float4(0.f, 0.f, 0.f, 0.f);
    int e0 = rp[i], e1 = rp[i + 1];
    for (int e = e0 + grp; e < e1; e += 4) {
        int c = ccol[e];
        float4 gc = g4[(size_t)c * 16 + sl];
        float wsl = dvi.y * dinv2[c].y;
        ga.x = fmaf(wsl, gc.x, ga.x); ga.y = fmaf(wsl, gc.y, ga.y);
        ga.z = fmaf(wsl, gc.z, ga.z); ga.w = fmaf(wsl, gc.w, ga.w);
    }
#pragma unroll
    for (int off = 16; off <= 32; off <<= 1) {
        ga.x += __shfl_xor(ga.x, off); ga.y += __shfl_xor(ga.y, off);
        ga.z += __shfl_xor(ga.z, off); ga.w += __shfl_xor(ga.w, off);
    }
    if (lane < 16) {
        float ws = dvi.y * dvi.y;
        float4 gi = g4[(size_t)i * 16 + sl];
        float4 pv = ((const float4*)part)[(size_t)i * 16 + sl];
        float4 o;
        o.x = pv.x + 0.14f * fmaf(ws, gi.x, ga.x);
        o.y = pv.y + 0.14f * fmaf(ws, gi.y, ga.y);
        o.z = pv.z + 0.14f * fmaf(ws, gi.z, ga.z);
        o.w = pv.w + 0.14f * fmaf(ws, gi.w, ga.w);
        ((float4*)xo)[(size_t)i * 16 + sl] = o;
    }
}

// ---- out = log_softmax(relu(xk) @ W3) ----
__global__ __launch_bounds__(256) void k_out(const float* __restrict__ xk,
                                             const float* __restrict__ W3,
                                             float* __restrict__ out, int N, int C) {
    __shared__ float sW3[64 * 40];
    __shared__ float sbuf[4][64];
    for (int t = threadIdx.x; t < 64 * 40; t += 256) sW3[t] = W3[t];
    __syncthreads();
    int wid = threadIdx.x >> 6, f = threadIdx.x & 63;
    int i = blockIdx.x * 4 + wid;
    bool ok = i < N;
    int ii = ok ? i : 0;
    float xv = fmaxf(xk[(size_t)ii * 64 + f], 0.f);
    sbuf[wid][f] = xv;
    __syncthreads();
    float acc = 0.f;
    if (f < C) {
#pragma unroll
        for (int k = 0; k < 64; ++k) acc = fmaf(sbuf[wid][k], sW3[k * 40 + f], acc);
    }
    float m = (f < C) ? acc : -INFINITY;
#pragma unroll
    for (int off = 32; off; off >>= 1) m = fmaxf(m, __shfl_xor(m, off));
    float ex = (f < C) ? __expf(acc - m) : 0.f;
    float s = ex;
#pragma unroll
    for (int off = 32; off; off >>= 1) s += __shfl_xor(s, off);
    if (ok && f < C) out[(size_t)i * C + f] = acc - m - logf(s);
}

extern "C" void kernel_launch(void* const* d_in, const int* in_sizes, int n_in,
                              void* d_out, int out_size, void* d_ws, size_t ws_size,
                              hipStream_t stream) {
    const float* x  = (const float*)d_in[0];
    const int*   ei = (const int*)d_in[1];
    const float* W1 = (const float*)d_in[2];
    const float* W2 = (const float*)d_in[3];
    const float* W3 = (const float*)d_in[4];
    float* out = (float*)d_out;

    const int N = in_sizes[0] / 64;        // F = 64
    const int E = in_sizes[1] / 2;
    const int C = in_sizes[4] / 64;        // 40
    const int* row = ei;
    const int* col = ei + E;

    // workspace carve-out (256B aligned)
    char* w = (char*)d_ws;
    auto alloc = [&](size_t bytes) -> char* {
        char* p = w;
        w += (bytes + 255) & ~(size_t)255;
        return p;
    };
    int*    cnt    = (int*)alloc((size_t)N * 4);
    int*    deg    = (int*)alloc((size_t)N * 4);
    int*    rp     = (int*)alloc((size_t)(N + 1) * 4);
    int*    cursor = (int*)alloc((size_t)N * 4);
    int*    bsums  = (int*)alloc(4096);
    float2* dinv2  = (float2*)alloc((size_t)N * 8);
    int*    ccol   = (int*)alloc((size_t)E * 4);
    float*  h      = (float*)alloc((size_t)N * 64 * 4);
    float*  xa     = (float*)alloc((size_t)N * 64 * 4);
    float*  g      = (float*)alloc((size_t)N * 64 * 4);
    float*  part   = (float*)alloc((size_t)N * 64 * 4);
    (void)ws_size; (void)n_in; (void)out_size;

    hipMemsetAsync(cnt, 0, (size_t)N * 4, stream);
    hipMemsetAsync(deg, 0, (size_t)N * 4, stream);

    const int eb    = (E + 255) / 256;
    const int nb256 = (N + 255) / 256;
    const int nb4   = (N + 3) / 4;

    k_count<<<eb, 256, 0, stream>>>(row, col, cnt, deg, E);
    k_dinv<<<nb256, 256, 0, stream>>>(deg, dinv2, N);
    k_scan1<<<nb256, 256, 0, stream>>>(cnt, rp, bsums, N);
    k_scan2<<<1, 512, 0, stream>>>(bsums, nb256);
    k_scan3<<<nb256, 256, 0, stream>>>(rp, cursor, bsums, N, E);
    k_fill<<<eb, 256, 0, stream>>>(row, col, cursor, ccol, E);

    k_mlp<<<nb4, 256, 0, stream>>>(x, W1, W2, h, N);

    const float* cur = h;
    for (int k = 0; k < 4; ++k) {
        k_step1<<<nb4, 256, 0, stream>>>(cur, h, rp, ccol, dinv2, g, part, N);
        k_step2<<<nb4, 256, 0, stream>>>(g, part, rp, ccol, dinv2, xa, N);
        cur = xa;   // k_step2 writes in place thereafter (it never reads xk)
    }

    k_out<<<nb4, 256, 0, stream>>>(cur, W3, out, N, C);
}

// Round 3
// 932.584 us; speedup vs baseline: 1.9799x; 1.0941x over previous
//
#include <hip/hip_runtime.h>
#include <math.h>

// SimpleGCN diffusion on MI355X — round 3.
// Key changes vs round 2:
//  - fill precomputes per-edge weights (w_ns, w_sl as full dinv[row]*dinv[col] products)
//    -> step kernels have NO dependent dinv gather in the inner loop
//  - edge loop unrolled x2 (8 edges in flight per wave), branchless tail via clamp+zero-weight
//  - k_mlp / k_out loop rows inside 1024 blocks (amortize LDS weight staging)

__global__ void k_count(const int* __restrict__ row, const int* __restrict__ col,
                        int* __restrict__ cnt, int* __restrict__ deg, int E) {
    int e = blockIdx.x * blockDim.x + threadIdx.x;
    if (e < E) {
        atomicAdd(&cnt[row[e]], 1);   // CSR row sizes
        atomicAdd(&deg[col[e]], 1);   // gcn_norm degree (reference segments over col)
    }
}

__global__ void k_dinv(const int* __restrict__ deg, float2* __restrict__ dinv2, int N) {
    int i = blockIdx.x * blockDim.x + threadIdx.x;
    if (i < N) {
        int d = deg[i];
        float2 v;
        v.x = d > 0 ? rsqrtf((float)d) : 0.0f;     // no-self-loop norm
        v.y = rsqrtf((float)(d + 1));              // self-loop norm
        dinv2[i] = v;
    }
}

// ---- 2-level exclusive scan over N row counts ----
__global__ void k_scan1(const int* __restrict__ cnt, int* __restrict__ excl,
                        int* __restrict__ bsums, int N) {
    __shared__ int s[256];
    int i = blockIdx.x * 256 + threadIdx.x;
    int v = (i < N) ? cnt[i] : 0;
    s[threadIdx.x] = v;
    __syncthreads();
    for (int off = 1; off < 256; off <<= 1) {
        int t = (threadIdx.x >= off) ? s[threadIdx.x - off] : 0;
        __syncthreads();
        s[threadIdx.x] += t;
        __syncthreads();
    }
    if (i < N) excl[i] = s[threadIdx.x] - v;
    if (threadIdx.x == 255) bsums[blockIdx.x] = s[255];
}

__global__ void k_scan2(int* __restrict__ bsums, int nb) {
    __shared__ int s[512];
    int t = threadIdx.x;
    int v = (t < nb) ? bsums[t] : 0;
    s[t] = v;
    __syncthreads();
    for (int off = 1; off < 512; off <<= 1) {
        int u = (t >= off) ? s[t - off] : 0;
        __syncthreads();
        s[t] += u;
        __syncthreads();
    }
    if (t < nb) bsums[t] = s[t] - v;
}

__global__ void k_scan3(int* __restrict__ rp, int* __restrict__ cursor,
                        const int* __restrict__ bsums, int N, int E) {
    int i = blockIdx.x * 256 + threadIdx.x;
    if (i < N) {
        int v = rp[i] + bsums[blockIdx.x];
        rp[i] = v;
        cursor[i] = v;
    }
    if (i == 0) rp[N] = E;
}

// ---- fill CSR: edata[p] = {col, w_sl}, wns[p] = w_ns (full products) ----
__global__ void k_fill(const int* __restrict__ row, const int* __restrict__ col,
                       int* __restrict__ cursor, const float2* __restrict__ dinv2,
                       int2* __restrict__ edata, float* __restrict__ wns, int E) {
    int e = blockIdx.x * blockDim.x + threadIdx.x;
    if (e < E) {
        int r = row[e], c = col[e];
        float2 dr = dinv2[r], dc = dinv2[c];
        int p = atomicAdd(&cursor[r], 1);
        int2 ed;
        ed.x = c;
        ed.y = __float_as_int(dr.y * dc.y);   // w_sl
        edata[p] = ed;
        wns[p] = dr.x * dc.x;                 // w_ns
    }
}

// ---- h = relu(x @ W1) @ W2 ; wave-per-row, weights in LDS, rows looped ----
__global__ __launch_bounds__(256) void k_mlp(const float* __restrict__ x,
                                             const float* __restrict__ W1,
                                             const float* __restrict__ W2,
                                             float* __restrict__ h, int N, int nblk) {
    __shared__ float sW1[64 * 64];
    __shared__ float sW2[64 * 64];
    __shared__ float sbuf[4][64];
    for (int t = threadIdx.x; t < 4096; t += 256) { sW1[t] = W1[t]; sW2[t] = W2[t]; }
    __syncthreads();
    int wid = threadIdx.x >> 6, f = threadIdx.x & 63;
    for (int i0 = blockIdx.x * 4; i0 < N; i0 += nblk * 4) {
        int i = i0 + wid;
        bool ok = i < N;
        int ii = ok ? i : 0;
        float xr = x[(size_t)ii * 64 + f];
        sbuf[wid][f] = xr;
        __syncthreads();
        float t0 = 0.f;
#pragma unroll
        for (int k = 0; k < 64; ++k) t0 = fmaf(sbuf[wid][k], sW1[k * 64 + f], t0);
        t0 = fmaxf(t0, 0.f);
        __syncthreads();
        sbuf[wid][f] = t0;
        __syncthreads();
        float hv = 0.f;
#pragma unroll
        for (int k = 0; k < 64; ++k) hv = fmaf(sbuf[wid][k], sW2[k * 64 + f], hv);
        if (ok) h[(size_t)i * 64 + f] = hv;
        __syncthreads();
    }
}

// ---- K1: gather xk[col] once; accumulate gradient g AND Ax; write g, part ----
__global__ __launch_bounds__(256) void k_step1(const float* __restrict__ xk,
                                               const float* __restrict__ h,
                                               const int* __restrict__ rp,
                                               const int2* __restrict__ edata,
                                               const float* __restrict__ wns,
                                               const float2* __restrict__ dinv2,
                                               float* __restrict__ g,
                                               float* __restrict__ part, int N) {
    int i = (blockIdx.x * blockDim.x + threadIdx.x) >> 6;
    if (i >= N) return;
    int lane = threadIdx.x & 63;
    int grp = lane >> 4, sl = lane & 15;
    const float4* xk4 = (const float4*)xk;
    float4 xi = xk4[(size_t)i * 16 + sl];
    float2 dvi = dinv2[i];
    float4 ga = make_float4(0.f, 0.f, 0.f, 0.f);
    float4 aa = make_float4(0.f, 0.f, 0.f, 0.f);
    int e0 = rp[i], e1 = rp[i + 1];
    int last = e1 - 1;
    for (int e = e0; e < e1; e += 8) {
        int ea = e + grp, eb = ea + 4;
        bool va = ea <= last, vb = eb <= last;
        int ia = va ? ea : last, ib = vb ? eb : last;
        int2 Ea = edata[ia];
        int2 Eb = edata[ib];
        float wna = wns[ia], wnb = wns[ib];
        float4 xa4 = xk4[(size_t)Ea.x * 16 + sl];
        float4 xb4 = xk4[(size_t)Eb.x * 16 + sl];
        float wsa = __int_as_float(Ea.y), wsb = __int_as_float(Eb.y);
        if (!va) { wna = 0.f; wsa = 0.f; }
        if (!vb) { wnb = 0.f; wsb = 0.f; }
        // edge a
        float dax = xa4.x - xi.x, day = xa4.y - xi.y, daz = xa4.z - xi.z, daw = xa4.w - xi.w;
        float n2a = dax * dax + day * day + daz * daz + daw * daw;
        // edge b
        float dbx = xb4.x - xi.x, dby = xb4.y - xi.y, dbz = xb4.z - xi.z, dbw = xb4.w - xi.w;
        float n2b = dbx * dbx + dby * dby + dbz * dbz + dbw * dbw;
        n2a += __shfl_xor(n2a, 1);  n2b += __shfl_xor(n2b, 1);
        n2a += __shfl_xor(n2a, 2);  n2b += __shfl_xor(n2b, 2);
        n2a += __shfl_xor(n2a, 4);  n2b += __shfl_xor(n2b, 4);
        n2a += __shfl_xor(n2a, 8);  n2b += __shfl_xor(n2b, 8);
        float coefa = wna * 0.5f * __expf(-0.5f * n2a);
        float coefb = wnb * 0.5f * __expf(-0.5f * n2b);
        ga.x = fmaf(coefa, dax, ga.x); ga.y = fmaf(coefa, day, ga.y);
        ga.z = fmaf(coefa, daz, ga.z); ga.w = fmaf(coefa, daw, ga.w);
        ga.x = fmaf(coefb, dbx, ga.x); ga.y = fmaf(coefb, dby, ga.y);
        ga.z = fmaf(coefb, dbz, ga.z); ga.w = fmaf(coefb, dbw, ga.w);
        aa.x = fmaf(wsa, xa4.x, aa.x); aa.y = fmaf(wsa, xa4.y, aa.y);
        aa.z = fmaf(wsa, xa4.z, aa.z); aa.w = fmaf(wsa, xa4.w, aa.w);
        aa.x = fmaf(wsb, xb4.x, aa.x); aa.y = fmaf(wsb, xb4.y, aa.y);
        aa.z = fmaf(wsb, xb4.z, aa.z); aa.w = fmaf(wsb, xb4.w, aa.w);
    }
#pragma unroll
    for (int off = 16; off <= 32; off <<= 1) {
        ga.x += __shfl_xor(ga.x, off); ga.y += __shfl_xor(ga.y, off);
        ga.z += __shfl_xor(ga.z, off); ga.w += __shfl_xor(ga.w, off);
        aa.x += __shfl_xor(aa.x, off); aa.y += __shfl_xor(aa.y, off);
        aa.z += __shfl_xor(aa.z, off); aa.w += __shfl_xor(aa.w, off);
    }
    if (lane < 16) {
        float ws = dvi.y * dvi.y;   // self-loop weight = 1/(deg+1)
        float4 hv = ((const float4*)h)[(size_t)i * 16 + sl];
        float4 o;
        o.x = 0.1f * hv.x + 0.2f * xi.x + 0.7f * fmaf(ws, xi.x, aa.x);
        o.y = 0.1f * hv.y + 0.2f * xi.y + 0.7f * fmaf(ws, xi.y, aa.y);
        o.z = 0.1f * hv.z + 0.2f * xi.z + 0.7f * fmaf(ws, xi.z, aa.z);
        o.w = 0.1f * hv.w + 0.2f * xi.w + 0.7f * fmaf(ws, xi.w, aa.w);
        ((float4*)g)[(size_t)i * 16 + sl] = ga;
        ((float4*)part)[(size_t)i * 16 + sl] = o;
    }
}

// ---- K2: gather g[col]; xo = part + 0.14*( ws*g[i] + sum_e w_sl*g[c] ) ----
__global__ __launch_bounds__(256) void k_step2(const float* __restrict__ g,
                                               const float* __restrict__ part,
                                               const int* __restrict__ rp,
                                               const int2* __restrict__ edata,
                                               const float2* __restrict__ dinv2,
                                               float* __restrict__ xo, int N) {
    int i = (blockIdx.x * blockDim.x + threadIdx.x) >> 6;
    if (i >= N) return;
    int lane = threadIdx.x & 63;
    int grp = lane >> 4, sl = lane & 15;
    const float4* g4 = (const float4*)g;
    float2 dvi = dinv2[i];
    float4 ga = make_float4(0.f, 0.f, 0.f, 0.f);
    int e0 = rp[i], e1 = rp[i + 1];
    int last = e1 - 1;
    for (int e = e0; e < e1; e += 8) {
        int ea = e + grp, eb = ea + 4;
        bool va = ea <= last, vb = eb <= last;
        int ia = va ? ea : last, ib = vb ? eb : last;
        int2 Ea = edata[ia];
        int2 Eb = edata[ib];
        float4 ga4 = g4[(size_t)Ea.x * 16 + sl];
        float4 gb4 = g4[(size_t)Eb.x * 16 + sl];
        float wsa = __int_as_float(Ea.y), wsb = __int_as_float(Eb.y);
        if (!va) wsa = 0.f;
        if (!vb) wsb = 0.f;
        ga.x = fmaf(wsa, ga4.x, ga.x); ga.y = fmaf(wsa, ga4.y, ga.y);
        ga.z = fmaf(wsa, ga4.z, ga.z); ga.w = fmaf(wsa, ga4.w, ga.w);
        ga.x = fmaf(wsb, gb4.x, ga.x); ga.y = fmaf(wsb, gb4.y, ga.y);
        ga.z = fmaf(wsb, gb4.z, ga.z); ga.w = fmaf(wsb, gb4.w, ga.w);
    }
#pragma unroll
    for (int off = 16; off <= 32; off <<= 1) {
        ga.x += __shfl_xor(ga.x, off); ga.y += __shfl_xor(ga.y, off);
        ga.z += __shfl_xor(ga.z, off); ga.w += __shfl_xor(ga.w, off);
    }
    if (lane < 16) {
        float ws = dvi.y * dvi.y;
        float4 gi = g4[(size_t)i * 16 + sl];
        float4 pv = ((const float4*)part)[(size_t)i * 16 + sl];
        float4 o;
        o.x = pv.x + 0.14f * fmaf(ws, gi.x, ga.x);
        o.y = pv.y + 0.14f * fmaf(ws, gi.y, ga.y);
        o.z = pv.z + 0.14f * fmaf(ws, gi.z, ga.z);
        o.w = pv.w + 0.14f * fmaf(ws, gi.w, ga.w);
        ((float4*)xo)[(size_t)i * 16 + sl] = o;
    }
}

// ---- out = log_softmax(relu(xk) @ W3) ; rows looped ----
__global__ __launch_bounds__(256) void k_out(const float* __restrict__ xk,
                                             const float* __restrict__ W3,
                                             float* __restrict__ out, int N, int C,
                                             int nblk) {
    __shared__ float sW3[64 * 40];
    __shared__ float sbuf[4][64];
    for (int t = threadIdx.x; t < 64 * 40; t += 256) sW3[t] = W3[t];
    __syncthreads();
    int wid = threadIdx.x >> 6, f = threadIdx.x & 63;
    for (int i0 = blockIdx.x * 4; i0 < N; i0 += nblk * 4) {
        int i = i0 + wid;
        bool ok = i < N;
        int ii = ok ? i : 0;
        float xv = fmaxf(xk[(size_t)ii * 64 + f], 0.f);
        sbuf[wid][f] = xv;
        __syncthreads();
        float acc = 0.f;
        if (f < C) {
#pragma unroll
            for (int k = 0; k < 64; ++k) acc = fmaf(sbuf[wid][k], sW3[k * 40 + f], acc);
        }
        float m = (f < C) ? acc : -INFINITY;
#pragma unroll
        for (int off = 32; off; off >>= 1) m = fmaxf(m, __shfl_xor(m, off));
        float ex = (f < C) ? __expf(acc - m) : 0.f;
        float s = ex;
#pragma unroll
        for (int off = 32; off; off >>= 1) s += __shfl_xor(s, off);
        if (ok && f < C) out[(size_t)i * C + f] = acc - m - logf(s);
        __syncthreads();
    }
}

extern "C" void kernel_launch(void* const* d_in, const int* in_sizes, int n_in,
                              void* d_out, int out_size, void* d_ws, size_t ws_size,
                              hipStream_t stream) {
    const float* x  = (const float*)d_in[0];
    const int*   ei = (const int*)d_in[1];
    const float* W1 = (const float*)d_in[2];
    const float* W2 = (const float*)d_in[3];
    const float* W3 = (const float*)d_in[4];
    float* out = (float*)d_out;

    const int N = in_sizes[0] / 64;        // F = 64
    const int E = in_sizes[1] / 2;
    const int C = in_sizes[4] / 64;        // 40
    const int* row = ei;
    const int* col = ei + E;

    // workspace carve-out (256B aligned)
    char* w = (char*)d_ws;
    auto alloc = [&](size_t bytes) -> char* {
        char* p = w;
        w += (bytes + 255) & ~(size_t)255;
        return p;
    };
    int*    cnt    = (int*)alloc((size_t)N * 4);
    int*    deg    = (int*)alloc((size_t)N * 4);
    int*    rp     = (int*)alloc((size_t)(N + 1) * 4);
    int*    cursor = (int*)alloc((size_t)N * 4);
    int*    bsums  = (int*)alloc(4096);
    float2* dinv2  = (float2*)alloc((size_t)N * 8);
    int2*   edata  = (int2*)alloc((size_t)E * 8);
    float*  wns    = (float*)alloc((size_t)E * 4);
    float*  h      = (float*)alloc((size_t)N * 64 * 4);
    float*  xa     = (float*)alloc((size_t)N * 64 * 4);
    float*  xb     = (float*)alloc((size_t)N * 64 * 4);
    float*  g      = (float*)alloc((size_t)N * 64 * 4);
    (void)ws_size; (void)n_in; (void)out_size;

    hipMemsetAsync(cnt, 0, (size_t)N * 4, stream);
    hipMemsetAsync(deg, 0, (size_t)N * 4, stream);

    const int eb    = (E + 255) / 256;
    const int nb256 = (N + 255) / 256;
    const int nb4   = (N + 3) / 4;

    k_count<<<eb, 256, 0, stream>>>(row, col, cnt, deg, E);
    k_dinv<<<nb256, 256, 0, stream>>>(deg, dinv2, N);
    k_scan1<<<nb256, 256, 0, stream>>>(cnt, rp, bsums, N);
    k_scan2<<<1, 512, 0, stream>>>(bsums, nb256);
    k_scan3<<<nb256, 256, 0, stream>>>(rp, cursor, bsums, N, E);
    k_fill<<<eb, 256, 0, stream>>>(row, col, cursor, dinv2, edata, wns, E);

    k_mlp<<<1024, 256, 0, stream>>>(x, W1, W2, h, N, 1024);

    const float* cur = h;
    float* pp = xb;   // 'part' ping-pong target (must not alias cur)
    for (int k = 0; k < 4; ++k) {
        k_step1<<<nb4, 256, 0, stream>>>(cur, h, rp, edata, wns, dinv2, g, pp, N);
        k_step2<<<nb4, 256, 0, stream>>>(g, pp, rp, edata, dinv2, pp, N);
        cur = pp;
        pp = (pp == xa) ? xb : xa;
    }

    k_out<<<1024, 256, 0, stream>>>(cur, W3, out, N, C, 1024);
}

// Round 4
// 789.859 us; speedup vs baseline: 2.3377x; 1.1807x over previous
//
#include <hip/hip_runtime.h>
#include <hip/hip_fp16.h>
#include <math.h>

// SimpleGCN diffusion on MI355X — round 4.
// vs round 3:
//  - k_count: cnt|deg packed into ONE u32 array (halves random-atomic line footprint)
//  - 8-byte edge records: {col, half(w_sl)<<16 | half(w_ns)}
//  - fp16 shadow buffers (xh for node features, gh for gradient) -> edge gathers
//    read 128B (2 lines) per edge instead of 256B (4 lines). Self terms stay fp32.
//  - explicit prefetch of next iteration's edge records in the step loops.

__global__ void k_count(const int* __restrict__ row, const int* __restrict__ col,
                        unsigned* __restrict__ packed, int E) {
    int e = blockIdx.x * blockDim.x + threadIdx.x;
    if (e < E) {
        atomicAdd(&packed[row[e]], 1u);          // low 16: CSR row size
        atomicAdd(&packed[col[e]], 1u << 16);    // high 16: gcn_norm degree (over col)
    }
}

__global__ void k_dinv(const unsigned* __restrict__ packed, float2* __restrict__ dinv2, int N) {
    int i = blockIdx.x * blockDim.x + threadIdx.x;
    if (i < N) {
        int d = (int)(packed[i] >> 16);
        float2 v;
        v.x = d > 0 ? rsqrtf((float)d) : 0.0f;     // no-self-loop norm
        v.y = rsqrtf((float)(d + 1));              // self-loop norm
        dinv2[i] = v;
    }
}

// ---- 2-level exclusive scan over N row counts (low 16 bits of packed) ----
__global__ void k_scan1(const unsigned* __restrict__ packed, int* __restrict__ excl,
                        int* __restrict__ bsums, int N) {
    __shared__ int s[256];
    int i = blockIdx.x * 256 + threadIdx.x;
    int v = (i < N) ? (int)(packed[i] & 0xffffu) : 0;
    s[threadIdx.x] = v;
    __syncthreads();
    for (int off = 1; off < 256; off <<= 1) {
        int t = (threadIdx.x >= off) ? s[threadIdx.x - off] : 0;
        __syncthreads();
        s[threadIdx.x] += t;
        __syncthreads();
    }
    if (i < N) excl[i] = s[threadIdx.x] - v;
    if (threadIdx.x == 255) bsums[blockIdx.x] = s[255];
}

__global__ void k_scan2(int* __restrict__ bsums, int nb) {
    __shared__ int s[512];
    int t = threadIdx.x;
    int v = (t < nb) ? bsums[t] : 0;
    s[t] = v;
    __syncthreads();
    for (int off = 1; off < 512; off <<= 1) {
        int u = (t >= off) ? s[t - off] : 0;
        __syncthreads();
        s[t] += u;
        __syncthreads();
    }
    if (t < nb) bsums[t] = s[t] - v;
}

__global__ void k_scan3(int* __restrict__ rp, int* __restrict__ cursor,
                        const int* __restrict__ bsums, int N, int E) {
    int i = blockIdx.x * 256 + threadIdx.x;
    if (i < N) {
        int v = rp[i] + bsums[blockIdx.x];
        rp[i] = v;
        cursor[i] = v;
    }
    if (i == 0) rp[N] = E;
}

// ---- fill CSR: edata[p] = {col, half(w_sl)<<16 | half(w_ns)} ----
__global__ void k_fill(const int* __restrict__ row, const int* __restrict__ col,
                       int* __restrict__ cursor, const float2* __restrict__ dinv2,
                       int2* __restrict__ edata, int E) {
    int e = blockIdx.x * blockDim.x + threadIdx.x;
    if (e < E) {
        int r = row[e], c = col[e];
        float2 dr = dinv2[r], dc = dinv2[c];
        unsigned wsl = __half_as_ushort(__float2half_rn(dr.y * dc.y));
        unsigned wns = __half_as_ushort(__float2half_rn(dr.x * dc.x));
        int p = atomicAdd(&cursor[r], 1);
        edata[p] = make_int2(c, (int)((wsl << 16) | wns));
    }
}

// ---- h = relu(x @ W1) @ W2 ; also writes fp16 shadow xh ----
__global__ __launch_bounds__(256) void k_mlp(const float* __restrict__ x,
                                             const float* __restrict__ W1,
                                             const float* __restrict__ W2,
                                             float* __restrict__ h,
                                             unsigned* __restrict__ xh,  // N*32 u32 (fp16 x2)
                                             int N, int nblk) {
    __shared__ float sW1[64 * 64];
    __shared__ float sW2[64 * 64];
    __shared__ float sbuf[4][64];
    for (int t = threadIdx.x; t < 4096; t += 256) { sW1[t] = W1[t]; sW2[t] = W2[t]; }
    __syncthreads();
    int wid = threadIdx.x >> 6, f = threadIdx.x & 63;
    for (int i0 = blockIdx.x * 4; i0 < N; i0 += nblk * 4) {
        int i = i0 + wid;
        bool ok = i < N;
        int ii = ok ? i : 0;
        float xr = x[(size_t)ii * 64 + f];
        sbuf[wid][f] = xr;
        __syncthreads();
        float t0 = 0.f;
#pragma unroll
        for (int k = 0; k < 64; ++k) t0 = fmaf(sbuf[wid][k], sW1[k * 64 + f], t0);
        t0 = fmaxf(t0, 0.f);
        __syncthreads();
        sbuf[wid][f] = t0;
        __syncthreads();
        float hv = 0.f;
#pragma unroll
        for (int k = 0; k < 64; ++k) hv = fmaf(sbuf[wid][k], sW2[k * 64 + f], hv);
        float hn = __shfl_down(hv, 1);
        if (ok) {
            h[(size_t)i * 64 + f] = hv;
            if ((f & 1) == 0) {
                unsigned p = (unsigned)__half_as_ushort(__float2half_rn(hv)) |
                             ((unsigned)__half_as_ushort(__float2half_rn(hn)) << 16);
                xh[(size_t)i * 32 + (f >> 1)] = p;
            }
        }
        __syncthreads();
    }
}

__device__ __forceinline__ void unpack4(float2 r, float& a, float& b, float& c, float& d) {
    __half2 h0 = *reinterpret_cast<const __half2*>(&r.x);
    __half2 h1 = *reinterpret_cast<const __half2*>(&r.y);
    float2 f0 = __half22float2(h0), f1 = __half22float2(h1);
    a = f0.x; b = f0.y; c = f1.x; d = f1.y;
}

// ---- K1: gather xh[col] (fp16); accumulate gradient (->gh fp16) AND Ax (->part fp32) ----
__global__ __launch_bounds__(256) void k_step1(const float* __restrict__ xk,
                                               const float2* __restrict__ xh,
                                               const float* __restrict__ h,
                                               const int* __restrict__ rp,
                                               const int2* __restrict__ edata,
                                               const float2* __restrict__ dinv2,
                                               float2* __restrict__ gh,
                                               float* __restrict__ part, int N) {
    int i = (blockIdx.x * blockDim.x + threadIdx.x) >> 6;
    if (i >= N) return;
    int lane = threadIdx.x & 63;
    int grp = lane >> 4, sl = lane & 15;
    const float4* xk4 = (const float4*)xk;
    float4 xi = xk4[(size_t)i * 16 + sl];
    float2 dvi = dinv2[i];
    float4 ga = make_float4(0.f, 0.f, 0.f, 0.f);
    float4 aa = make_float4(0.f, 0.f, 0.f, 0.f);
    int e0 = rp[i], e1 = rp[i + 1];
    if (e0 < e1) {
        int last = e1 - 1;
        int2 Ea = edata[min(e0 + grp, last)];
        int2 Eb = edata[min(e0 + grp + 4, last)];
        for (int e = e0; e < e1; e += 8) {
            bool va = (e + grp) <= last, vb = (e + grp + 4) <= last;
            // issue both gathers
            float2 ra = xh[(size_t)Ea.x * 16 + sl];
            float2 rb = xh[(size_t)Eb.x * 16 + sl];
            // prefetch next records
            int2 En1 = edata[min(e + 8 + grp, last)];
            int2 En2 = edata[min(e + 12 + grp, last)];
            // weights (half2 packed: low=w_ns, high=w_sl)
            float2 wfa = __half22float2(*reinterpret_cast<const __half2*>(&Ea.y));
            float2 wfb = __half22float2(*reinterpret_cast<const __half2*>(&Eb.y));
            float wna = va ? wfa.x : 0.f, wsa = va ? wfa.y : 0.f;
            float wnb = vb ? wfb.x : 0.f, wsb = vb ? wfb.y : 0.f;
            float ax_, ay_, az_, aw_, bx_, by_, bz_, bw_;
            unpack4(ra, ax_, ay_, az_, aw_);
            unpack4(rb, bx_, by_, bz_, bw_);
            float dax = ax_ - xi.x, day = ay_ - xi.y, daz = az_ - xi.z, daw = aw_ - xi.w;
            float n2a = dax * dax + day * day + daz * daz + daw * daw;
            float dbx = bx_ - xi.x, dby = by_ - xi.y, dbz = bz_ - xi.z, dbw = bw_ - xi.w;
            float n2b = dbx * dbx + dby * dby + dbz * dbz + dbw * dbw;
            n2a += __shfl_xor(n2a, 1);  n2b += __shfl_xor(n2b, 1);
            n2a += __shfl_xor(n2a, 2);  n2b += __shfl_xor(n2b, 2);
            n2a += __shfl_xor(n2a, 4);  n2b += __shfl_xor(n2b, 4);
            n2a += __shfl_xor(n2a, 8);  n2b += __shfl_xor(n2b, 8);
            float coefa = wna * 0.5f * __expf(-0.5f * n2a);
            float coefb = wnb * 0.5f * __expf(-0.5f * n2b);
            ga.x = fmaf(coefa, dax, ga.x); ga.y = fmaf(coefa, day, ga.y);
            ga.z = fmaf(coefa, daz, ga.z); ga.w = fmaf(coefa, daw, ga.w);
            ga.x = fmaf(coefb, dbx, ga.x); ga.y = fmaf(coefb, dby, ga.y);
            ga.z = fmaf(coefb, dbz, ga.z); ga.w = fmaf(coefb, dbw, ga.w);
            aa.x = fmaf(wsa, ax_, aa.x); aa.y = fmaf(wsa, ay_, aa.y);
            aa.z = fmaf(wsa, az_, aa.z); aa.w = fmaf(wsa, aw_, aa.w);
            aa.x = fmaf(wsb, bx_, aa.x); aa.y = fmaf(wsb, by_, aa.y);
            aa.z = fmaf(wsb, bz_, aa.z); aa.w = fmaf(wsb, bw_, aa.w);
            Ea = En1; Eb = En2;
        }
    }
#pragma unroll
    for (int off = 16; off <= 32; off <<= 1) {
        ga.x += __shfl_xor(ga.x, off); ga.y += __shfl_xor(ga.y, off);
        ga.z += __shfl_xor(ga.z, off); ga.w += __shfl_xor(ga.w, off);
        aa.x += __shfl_xor(aa.x, off); aa.y += __shfl_xor(aa.y, off);
        aa.z += __shfl_xor(aa.z, off); aa.w += __shfl_xor(aa.w, off);
    }
    if (lane < 16) {
        float ws = dvi.y * dvi.y;   // self-loop weight = 1/(deg+1)
        float4 hv = ((const float4*)h)[(size_t)i * 16 + sl];
        float4 o;
        o.x = 0.1f * hv.x + 0.2f * xi.x + 0.7f * fmaf(ws, xi.x, aa.x);
        o.y = 0.1f * hv.y + 0.2f * xi.y + 0.7f * fmaf(ws, xi.y, aa.y);
        o.z = 0.1f * hv.z + 0.2f * xi.z + 0.7f * fmaf(ws, xi.z, aa.z);
        o.w = 0.1f * hv.w + 0.2f * xi.w + 0.7f * fmaf(ws, xi.w, aa.w);
        ((float4*)part)[(size_t)i * 16 + sl] = o;
        unsigned lo = (unsigned)__half_as_ushort(__float2half_rn(ga.x)) |
                      ((unsigned)__half_as_ushort(__float2half_rn(ga.y)) << 16);
        unsigned hi = (unsigned)__half_as_ushort(__float2half_rn(ga.z)) |
                      ((unsigned)__half_as_ushort(__float2half_rn(ga.w)) << 16);
        float2 st;
        st.x = __uint_as_float(lo);
        st.y = __uint_as_float(hi);
        gh[(size_t)i * 16 + sl] = st;
    }
}

// ---- K2: gather gh[col] (fp16); xo = part + 0.14*(ws*g_i + Gx); write xo fp32 + xh fp16 ----
__global__ __launch_bounds__(256) void k_step2(const float2* __restrict__ gh,
                                               const float* __restrict__ part,
                                               const int* __restrict__ rp,
                                               const int2* __restrict__ edata,
                                               const float2* __restrict__ dinv2,
                                               float* __restrict__ xo,
                                               uint2* __restrict__ xh, int N) {
    int i = (blockIdx.x * blockDim.x + threadIdx.x) >> 6;
    if (i >= N) return;
    int lane = threadIdx.x & 63;
    int grp = lane >> 4, sl = lane & 15;
    float2 dvi = dinv2[i];
    float4 ga = make_float4(0.f, 0.f, 0.f, 0.f);
    int e0 = rp[i], e1 = rp[i + 1];
    if (e0 < e1) {
        int last = e1 - 1;
        int2 Ea = edata[min(e0 + grp, last)];
        int2 Eb = edata[min(e0 + grp + 4, last)];
        for (int e = e0; e < e1; e += 8) {
            bool va = (e + grp) <= last, vb = (e + grp + 4) <= last;
            float2 ra = gh[(size_t)Ea.x * 16 + sl];
            float2 rb = gh[(size_t)Eb.x * 16 + sl];
            int2 En1 = edata[min(e + 8 + grp, last)];
            int2 En2 = edata[min(e + 12 + grp, last)];
            float2 wfa = __half22float2(*reinterpret_cast<const __half2*>(&Ea.y));
            float2 wfb = __half22float2(*reinterpret_cast<const __half2*>(&Eb.y));
            float wsa = va ? wfa.y : 0.f;
            float wsb = vb ? wfb.y : 0.f;
            float ax_, ay_, az_, aw_, bx_, by_, bz_, bw_;
            unpack4(ra, ax_, ay_, az_, aw_);
            unpack4(rb, bx_, by_, bz_, bw_);
            ga.x = fmaf(wsa, ax_, ga.x); ga.y = fmaf(wsa, ay_, ga.y);
            ga.z = fmaf(wsa, az_, ga.z); ga.w = fmaf(wsa, aw_, ga.w);
            ga.x = fmaf(wsb, bx_, ga.x); ga.y = fmaf(wsb, by_, ga.y);
            ga.z = fmaf(wsb, bz_, ga.z); ga.w = fmaf(wsb, bw_, ga.w);
            Ea = En1; Eb = En2;
        }
    }
#pragma unroll
    for (int off = 16; off <= 32; off <<= 1) {
        ga.x += __shfl_xor(ga.x, off); ga.y += __shfl_xor(ga.y, off);
        ga.z += __shfl_xor(ga.z, off); ga.w += __shfl_xor(ga.w, off);
    }
    if (lane < 16) {
        float ws = dvi.y * dvi.y;
        float gx_, gy_, gz_, gw_;
        unpack4(gh[(size_t)i * 16 + sl], gx_, gy_, gz_, gw_);
        float4 pv = ((const float4*)part)[(size_t)i * 16 + sl];
        float4 o;
        o.x = pv.x + 0.14f * fmaf(ws, gx_, ga.x);
        o.y = pv.y + 0.14f * fmaf(ws, gy_, ga.y);
        o.z = pv.z + 0.14f * fmaf(ws, gz_, ga.z);
        o.w = pv.w + 0.14f * fmaf(ws, gw_, ga.w);
        ((float4*)xo)[(size_t)i * 16 + sl] = o;
        unsigned lo = (unsigned)__half_as_ushort(__float2half_rn(o.x)) |
                      ((unsigned)__half_as_ushort(__float2half_rn(o.y)) << 16);
        unsigned hi = (unsigned)__half_as_ushort(__float2half_rn(o.z)) |
                      ((unsigned)__half_as_ushort(__float2half_rn(o.w)) << 16);
        xh[(size_t)i * 16 + sl] = make_uint2(lo, hi);
    }
}

// ---- out = log_softmax(relu(xk) @ W3) ; rows looped ----
__global__ __launch_bounds__(256) void k_out(const float* __restrict__ xk,
                                             const float* __restrict__ W3,
                                             float* __restrict__ out, int N, int C,
                                             int nblk) {
    __shared__ float sW3[64 * 40];
    __shared__ float sbuf[4][64];
    for (int t = threadIdx.x; t < 64 * 40; t += 256) sW3[t] = W3[t];
    __syncthreads();
    int wid = threadIdx.x >> 6, f = threadIdx.x & 63;
    for (int i0 = blockIdx.x * 4; i0 < N; i0 += nblk * 4) {
        int i = i0 + wid;
        bool ok = i < N;
        int ii = ok ? i : 0;
        float xv = fmaxf(xk[(size_t)ii * 64 + f], 0.f);
        sbuf[wid][f] = xv;
        __syncthreads();
        float acc = 0.f;
        if (f < C) {
#pragma unroll
            for (int k = 0; k < 64; ++k) acc = fmaf(sbuf[wid][k], sW3[k * 40 + f], acc);
        }
        float m = (f < C) ? acc : -INFINITY;
#pragma unroll
        for (int off = 32; off; off >>= 1) m = fmaxf(m, __shfl_xor(m, off));
        float ex = (f < C) ? __expf(acc - m) : 0.f;
        float s = ex;
#pragma unroll
        for (int off = 32; off; off >>= 1) s += __shfl_xor(s, off);
        if (ok && f < C) out[(size_t)i * C + f] = acc - m - logf(s);
        __syncthreads();
    }
}

extern "C" void kernel_launch(void* const* d_in, const int* in_sizes, int n_in,
                              void* d_out, int out_size, void* d_ws, size_t ws_size,
                              hipStream_t stream) {
    const float* x  = (const float*)d_in[0];
    const int*   ei = (const int*)d_in[1];
    const float* W1 = (const float*)d_in[2];
    const float* W2 = (const float*)d_in[3];
    const float* W3 = (const float*)d_in[4];
    float* out = (float*)d_out;

    const int N = in_sizes[0] / 64;        // F = 64
    const int E = in_sizes[1] / 2;
    const int C = in_sizes[4] / 64;        // 40
    const int* row = ei;
    const int* col = ei + E;

    // workspace carve-out (256B aligned)
    char* w = (char*)d_ws;
    auto alloc = [&](size_t bytes) -> char* {
        char* p = w;
        w += (bytes + 255) & ~(size_t)255;
        return p;
    };
    unsigned* packed = (unsigned*)alloc((size_t)N * 4);
    int*      rp     = (int*)alloc((size_t)(N + 1) * 4);
    int*      cursor = (int*)alloc((size_t)N * 4);
    int*      bsums  = (int*)alloc(4096);
    float2*   dinv2  = (float2*)alloc((size_t)N * 8);
    int2*     edata  = (int2*)alloc((size_t)E * 8);
    float*    h      = (float*)alloc((size_t)N * 64 * 4);
    float*    xa     = (float*)alloc((size_t)N * 64 * 4);
    float*    xb     = (float*)alloc((size_t)N * 64 * 4);
    float2*   gh     = (float2*)alloc((size_t)N * 128);   // fp16 gradient shadow
    float2*   xh     = (float2*)alloc((size_t)N * 128);   // fp16 feature shadow
    (void)ws_size; (void)n_in; (void)out_size;

    hipMemsetAsync(packed, 0, (size_t)N * 4, stream);

    const int eb    = (E + 255) / 256;
    const int nb256 = (N + 255) / 256;
    const int nb4   = (N + 3) / 4;

    k_count<<<eb, 256, 0, stream>>>(row, col, packed, E);
    k_dinv<<<nb256, 256, 0, stream>>>(packed, dinv2, N);
    k_scan1<<<nb256, 256, 0, stream>>>(packed, rp, bsums, N);
    k_scan2<<<1, 512, 0, stream>>>(bsums, nb256);
    k_scan3<<<nb256, 256, 0, stream>>>(rp, cursor, bsums, N, E);
    k_fill<<<eb, 256, 0, stream>>>(row, col, cursor, dinv2, edata, E);

    k_mlp<<<1024, 256, 0, stream>>>(x, W1, W2, h, (unsigned*)xh, N, 1024);

    const float* cur = h;
    float* pp = xb;   // 'part' / output ping-pong target (never aliases cur)
    for (int k = 0; k < 4; ++k) {
        k_step1<<<nb4, 256, 0, stream>>>(cur, xh, h, rp, edata, dinv2, gh, pp, N);
        k_step2<<<nb4, 256, 0, stream>>>(gh, pp, rp, edata, dinv2, pp, (uint2*)xh, N);
        cur = pp;
        pp = (pp == xa) ? xb : xa;
    }

    k_out<<<1024, 256, 0, stream>>>(cur, W3, out, N, C, 1024);
}